// Round 14
// baseline (64.239 us; speedup 1.0000x reference)
//
#include <hip/hip_runtime.h>
#include <hip/hip_bf16.h>

typedef __attribute__((ext_vector_type(8))) short bf16x8;
typedef __attribute__((ext_vector_type(16))) float f32x16;

#define DHEAD 64
#define L_SEQ 2048
// softmax scale 1/8 folded with log2(e): exp(x/8) == exp2(x*QSCALE)
#define QSCALE (0.125f * 1.44269504088896340736f)

// ws layout (contig-chunk schedule):
//  [4KB, 4KB+2MB)  ml float2[(bh*16+T)*4 + seg][128]
//  [4KB+2MB, +12.6MB) seg>=1 bf16 partial O, compact slots [768][128][64]
#define WS_ML_OFF   4096
#define WS_PART_OFF (4096 + 2048 * 128 * 8)
#define WS_NEED     ((size_t)WS_PART_OFF + (size_t)768 * 128 * 64 * 2)

union U4S8 { uint4 u; bf16x8 s; };

// Single-instruction f32x2 -> bf16x2 pack (RNE); no builtin on gfx950.
__device__ __forceinline__ unsigned pk2(float a, float b) {
    unsigned r;
    asm("v_cvt_pk_bf16_f32 %0, %1, %2" : "=v"(r) : "v"(a), "v"(b));
    return r;
}
// round f32 through bf16 (order-independent merge math)
__device__ __forceinline__ float bfrt(float x) {
    return __uint_as_float(pk2(x, x) << 16);
}
__device__ __forceinline__ float bf2f(unsigned short u) {
    return __uint_as_float((unsigned)u << 16);
}

__device__ __forceinline__ float fexp2(float x) {
#if __has_builtin(__builtin_amdgcn_exp2f)
    return __builtin_amdgcn_exp2f(x);
#else
    return __expf(x * 0.69314718055994530942f);
#endif
}

// Depth-4 trees, constant-index only (rule #20: runtime-indexing p -> scratch).
#define MAX16(P) fmaxf(fmaxf(fmaxf(fmaxf(P[0],P[1]),fmaxf(P[2],P[3])),          \
                             fmaxf(fmaxf(P[4],P[5]),fmaxf(P[6],P[7]))),         \
                       fmaxf(fmaxf(fmaxf(P[8],P[9]),fmaxf(P[10],P[11])),        \
                             fmaxf(fmaxf(P[12],P[13]),fmaxf(P[14],P[15]))))
#define SUM16(P) ((((P[0]+P[1])+(P[2]+P[3]))+((P[4]+P[5])+(P[6]+P[7])))         \
                + (((P[8]+P[9])+(P[10]+P[11]))+((P[12]+P[13])+(P[14]+P[15]))))

// Job table (per bh): 40 contiguous kv-chunks of <=4 tiles, LPT order
// (all len-4 first, then 3,2,1). Entry = (T<<2)|seg; chunk covers kv tiles
// [4*seg, min(4*seg+3, T)]. Round-13 lesson: makespan = longest job; with
// max=4 and avg=3.4, duty = 85% even with the whole grid co-resident
// (VGPR 84 + 32KB LDS -> 5 blocks/CU -> all 1280 blocks fit).
__constant__ unsigned char JOBS[40] = {
    // len 4 (28)
    (15<<2)|0, (15<<2)|1, (15<<2)|2, (15<<2)|3,
    (14<<2)|0, (14<<2)|1, (14<<2)|2,
    (13<<2)|0, (13<<2)|1, (13<<2)|2,
    (12<<2)|0, (12<<2)|1, (12<<2)|2,
    (11<<2)|0, (11<<2)|1, (11<<2)|2,
    (10<<2)|0, (10<<2)|1,
    ( 9<<2)|0, ( 9<<2)|1,
    ( 8<<2)|0, ( 8<<2)|1,
    ( 7<<2)|0, ( 7<<2)|1,
    ( 6<<2)|0, ( 5<<2)|0, ( 4<<2)|0, ( 3<<2)|0,
    // len 3 (4)
    (14<<2)|3, (10<<2)|2, ( 6<<2)|1, ( 2<<2)|0,
    // len 2 (4)
    (13<<2)|3, ( 9<<2)|2, ( 5<<2)|1, ( 1<<2)|0,
    // len 1 (4)
    (12<<2)|3, ( 8<<2)|2, ( 4<<2)|1, ( 0<<2)|0,
};

// LDS chunk map (all ds ops chunk_base + lane*16, conflict-free):
//  K chunk kb*4+kc, slot l: K[kb*32+(l&31)][kc*16+8*(l>>5)+j]
//  V chunk kv*2+dt, slot l: V[kv*16+8*(l>>5)+j][dt*32+(l&31)]  (kv=0..7)

template<int MODE>   // 2 = contig-chunk + merge; 0 = basic (no ws)
__global__ __launch_bounds__(256, 3)
void fattn_kernel(const float* __restrict__ Qg, const float* __restrict__ Kg,
                  const float* __restrict__ Vg, float* __restrict__ Og,
                  char* __restrict__ wsBase) {
    __shared__ uint4 sK4[16][64];
    __shared__ uint4 sV4[16][64];

    const int tid  = threadIdx.x;
    const int lane = tid & 63;
    const int w    = tid >> 6;     // wave -> rows 32w..32w+31 of this block's q-tile
    const int hi   = lane >> 5;
    const int c    = lane & 31;

    const int id  = blockIdx.x;
    const int bh  = (id & 7) + 8 * ((id >> 3) & 3);   // 4 bh per XCD

    int T, sg, kt0, d;
    if (MODE == 2) {
        const unsigned jb = JOBS[id >> 5];   // rank 0..39, LPT order
        T   = jb >> 2;
        sg  = jb & 3;
        kt0 = 4 * sg;
        d   = T - kt0 + 1; if (d > 4) d = 4;
    } else {                                  // basic fallback
        const int u_ = id >> 5;
        T = (u_ < 8) ? (15 - u_) : (u_ - 8);
        sg = 0; kt0 = 0; d = T + 1;
    }

    const size_t base = (size_t)bh * L_SEQ * DHEAD;
    const int q0w = T * 128 + w * 32;     // this wave's q rows

    // ---- Q fragments (B-operand), scale folded ----
    bf16x8 qf[4];
    {
        const float* Qrow = Qg + base + (size_t)(q0w + c) * DHEAD;
        #pragma unroll
        for (int kc = 0; kc < 4; ++kc) {
            float4 aa = *(const float4*)(Qrow + kc * 16 + hi * 8);
            float4 bb = *(const float4*)(Qrow + kc * 16 + hi * 8 + 4);
            U4S8 t;
            t.u = make_uint4(pk2(aa.x * QSCALE, aa.y * QSCALE),
                             pk2(aa.z * QSCALE, aa.w * QSCALE),
                             pk2(bb.x * QSCALE, bb.y * QSCALE),
                             pk2(bb.z * QSCALE, bb.w * QSCALE));
            qf[kc] = t.s;
        }
    }

    // ---- staging bases: thread (w,hi,c) ----
    const float* Kpb = Kg + base + (size_t)(32 * w + c) * DHEAD + 32 * hi;
    const float* Vpb = Vg + base + (size_t)(32 * w + 16 * hi) * DHEAD + c;

    auto stage_K = [&](int kt) {          // 32 floats live peak
        float4 rk[8];
        const float* Kp = Kpb + (size_t)kt * 128 * DHEAD;
        #pragma unroll
        for (int t = 0; t < 8; ++t) rk[t] = *(const float4*)(Kp + 4 * t);
        #pragma unroll
        for (int q = 0; q < 2; ++q)
            #pragma unroll
            for (int hh = 0; hh < 2; ++hh) {
                const float4 r0 = rk[4 * q + 2 * hh], r1 = rk[4 * q + 2 * hh + 1];
                sK4[w * 4 + 2 * hi + q][hh * 32 + c] =
                    make_uint4(pk2(r0.x, r0.y), pk2(r0.z, r0.w),
                               pk2(r1.x, r1.y), pk2(r1.z, r1.w));
            }
    };
    auto stage_V = [&](int kt) {          // 32 floats live peak
        float rv[32];
        const float* Vp = Vpb + (size_t)kt * 128 * DHEAD;
        #pragma unroll
        for (int j = 0; j < 16; ++j) {
            rv[j]      = Vp[j * DHEAD];
            rv[16 + j] = Vp[j * DHEAD + 32];
        }
        #pragma unroll
        for (int dt = 0; dt < 2; ++dt)
            #pragma unroll
            for (int hh = 0; hh < 2; ++hh) {
                const int b = 16 * dt + 8 * hh;
                sV4[(2 * w + hi) * 2 + dt][hh * 32 + c] =
                    make_uint4(pk2(rv[b + 0], rv[b + 1]), pk2(rv[b + 2], rv[b + 3]),
                               pk2(rv[b + 4], rv[b + 5]), pk2(rv[b + 6], rv[b + 7]));
            }
    };

    f32x16 o0 = {0,0,0,0,0,0,0,0,0,0,0,0,0,0,0,0};
    f32x16 o1 = o0;
    float m_r = -1e30f, l_r = 0.f;

    stage_K(kt0);
    stage_V(kt0);
    __syncthreads();

    for (int j = 0; j < d; ++j) {
        const int  kt   = kt0 + j;
        const bool pf   = (j + 1 < d);
        const bool diag = (kt == T);

        // two 64-key sub-passes over the staged 128-key tile (p[2][16] diet)
        #pragma unroll
        for (int sub = 0; sub < 2; ++sub) {
            const int lim = diag ? (w + 1 - 2 * sub) : 2;   // live 32-key blocks
            const int nkb = lim < 0 ? 0 : (lim > 2 ? 2 : lim);
            if (nkb > 0) {
                float p[2][16];

                // ---- S^T = K * Q^T (kb_global = 2*sub + i) ----
                __builtin_amdgcn_s_setprio(1);
                #pragma unroll
                for (int i = 0; i < 2; ++i) {
                    if (i < nkb) {
                        f32x16 s = {0,0,0,0,0,0,0,0,0,0,0,0,0,0,0,0};
                        #pragma unroll
                        for (int kc = 0; kc < 4; ++kc) {
                            U4S8 t; t.u = sK4[(2 * sub + i) * 4 + kc][lane];
                            s = __builtin_amdgcn_mfma_f32_32x32x16_bf16(t.s, qf[kc], s, 0, 0, 0);
                        }
                        #pragma unroll
                        for (int r = 0; r < 16; ++r) p[i][r] = s[r];
                    }
                }
                __builtin_amdgcn_s_setprio(0);

                // diagonal mask: compile-time index, runtime CONDITION only
                #pragma unroll
                for (int i = 0; i < 2; ++i) {
                    if (diag && (2 * sub + i) == w) {
                        #pragma unroll
                        for (int r = 0; r < 16; ++r) {
                            const int kk = (r & 3) + 8 * (r >> 2) + 4 * hi;
                            if (kk > c) p[i][r] = -1e30f;
                        }
                    }
                }

                // ---- online softmax over nkb*32 keys ----
                float mx = MAX16(p[0]);
                if (nkb > 1) mx = fmaxf(mx, MAX16(p[1]));
                mx = fmaxf(mx, __shfl_xor(mx, 32));

                if (__any(mx > m_r + 8.f)) {    // defer-max (T13)
                    const float mn    = fmaxf(m_r, mx);
                    const float alpha = fexp2(m_r - mn);
                    m_r  = mn;
                    l_r *= alpha;
                    #pragma unroll
                    for (int r = 0; r < 16; ++r) {
                        const float ab = __shfl(alpha, (r & 3) + 8 * (r >> 2) + 4 * hi);
                        o0[r] *= ab; o1[r] *= ab;
                    }
                }

                #pragma unroll
                for (int i = 0; i < 2; ++i) {
                    if (i < nkb) {
                        #pragma unroll
                        for (int r = 0; r < 16; ++r) p[i][r] = fexp2(p[i][r] - m_r);
                    }
                }
                float rs = SUM16(p[0]);
                if (nkb > 1) rs += SUM16(p[1]);
                rs += __shfl_xor(rs, 32);
                l_r += rs;

                // ---- P -> A-frags (permlane32_swap) + O += P V ----
                __builtin_amdgcn_s_setprio(1);
                #pragma unroll
                for (int kcl = 0; kcl < 4; ++kcl) {
                    if (kcl < 2 * nkb) {
                        const int i = kcl >> 1, bs = (kcl & 1) * 8;
                        unsigned a0 = pk2(p[i][bs + 0], p[i][bs + 1]);
                        unsigned a1 = pk2(p[i][bs + 2], p[i][bs + 3]);
                        unsigned b0 = pk2(p[i][bs + 4], p[i][bs + 5]);
                        unsigned b1 = pk2(p[i][bs + 6], p[i][bs + 7]);
                        asm("v_permlane32_swap_b32 %0, %1" : "+v"(a0), "+v"(b0));
                        asm("v_permlane32_swap_b32 %0, %1" : "+v"(a1), "+v"(b1));
                        U4S8 t;
                        t.u = make_uint4(a0, a1, b0, b1);
                        const int kv = 4 * sub + kcl;        // 16-key V slice
                        U4S8 tv0; tv0.u = sV4[kv * 2][lane];
                        o0 = __builtin_amdgcn_mfma_f32_32x32x16_bf16(t.s, tv0.s, o0, 0, 0, 0);
                        U4S8 tv1; tv1.u = sV4[kv * 2 + 1][lane];
                        o1 = __builtin_amdgcn_mfma_f32_32x32x16_bf16(t.s, tv1.s, o1, 0, 0, 0);
                    }
                }
                __builtin_amdgcn_s_setprio(0);
            }
        }

        if (pf) {                           // single buffer: drain reads, restage
            __syncthreads();
            stage_K(kt + 1);
            stage_V(kt + 1);
            __syncthreads();
        }
    }

    float* Op = Og + base;

    if (MODE == 0 || T <= 3) {
        // ---- single contributor: normalize, store final ----
        const float linv = 1.f / l_r;
        #pragma unroll
        for (int r = 0; r < 16; ++r) {
            const int   cr  = (r & 3) + 8 * (r >> 2) + 4 * hi;
            const float lb  = __shfl(linv, cr);
            const int   row = q0w + cr;
            Op[(size_t)row * DHEAD + c]      = o0[r] * lb;
            Op[(size_t)row * DHEAD + 32 + c] = o1[r] * lb;
        }
        return;
    }

    // ---- publish partial, write-only; merge_kernel combines ----
    const int f4 = (bh * 16 + T) * 4;
    float2* ml = (float2*)(wsBase + WS_ML_OFF);
    if (hi == 0) ml[(size_t)(f4 + sg) * 128 + w * 32 + c] = make_float2(m_r, l_r);
    if (sg == 0) {          // seg0 partial lives (bf16-rounded, unnormalized) in d_out
        #pragma unroll
        for (int r = 0; r < 16; ++r) {
            const int cr  = (r & 3) + 8 * (r >> 2) + 4 * hi;
            const int row = q0w + cr;
            Op[(size_t)row * DHEAD + c]      = bfrt(o0[r]);
            Op[(size_t)row * DHEAD + 32 + c] = bfrt(o1[r]);
        }
    } else {                // seg>=1 partial as bf16 in compact ws slot
        const int g  = T >> 2;
        const int ps = bh * 24 + 2 * g * (g - 1) + (T & 3) * g + (sg - 1);
        unsigned short* mp = (unsigned short*)(wsBase + WS_PART_OFF) + (size_t)ps * 128 * 64;
        #pragma unroll
        for (int r = 0; r < 16; ++r) {
            const int cr   = (r & 3) + 8 * (r >> 2) + 4 * hi;
            const int lrow = w * 32 + cr;
            mp[lrow * 64 + c]      = (unsigned short)pk2(o0[r], o0[r]);
            mp[lrow * 64 + 32 + c] = (unsigned short)pk2(o1[r], o1[r]);
        }
    }
}

// n-way streaming merge: one block per (bh,T), exact online-softmax combine.
__global__ __launch_bounds__(256)
void merge_kernel(float* __restrict__ Og, const char* __restrict__ wsBase) {
    const int blk = blockIdx.x;           // 512 = 32 bh x 16 T
    const int bh = blk >> 4, T = blk & 15;
    if (T <= 3) return;                   // single contributor wrote final
    const int n  = (T >> 2) + 1;          // contributors 2..4
    const int f4 = (bh * 16 + T) * 4;
    const int g  = T >> 2;
    const int psb = bh * 24 + 2 * g * (g - 1) + (T & 3) * g;

    const float2* ml = (const float2*)(wsBase + WS_ML_OFF);
    const unsigned short* part = (const unsigned short*)(wsBase + WS_PART_OFF);
    const unsigned short* p1 = part + (size_t)(psb + 0) * 128 * 64;
    const unsigned short* p2 = part + (size_t)(psb + 1) * 128 * 64;
    const unsigned short* p3 = part + (size_t)(psb + 2) * 128 * 64;
    float* Op = Og + ((size_t)bh * L_SEQ + (size_t)T * 128) * DHEAD;

    __shared__ float sA0[128], sA1[128], sA2[128], sA3[128], sLi[128];
    const int t = threadIdx.x;
    if (t < 128) {
        const float2 m0 = ml[(size_t)(f4 + 0) * 128 + t];
        const float2 m1 = ml[(size_t)(f4 + 1) * 128 + t];
        const float2 m2 = (n > 2) ? ml[(size_t)(f4 + 2) * 128 + t] : make_float2(-1e30f, 0.f);
        const float2 m3 = (n > 3) ? ml[(size_t)(f4 + 3) * 128 + t] : make_float2(-1e30f, 0.f);
        const float mM = fmaxf(fmaxf(m0.x, m1.x), fmaxf(m2.x, m3.x));
        const float a0 = fexp2(m0.x - mM), a1 = fexp2(m1.x - mM);
        const float a2 = fexp2(m2.x - mM), a3 = fexp2(m3.x - mM);
        sA0[t] = a0; sA1[t] = a1; sA2[t] = a2; sA3[t] = a3;
        sLi[t] = 1.f / (a0 * m0.y + a1 * m1.y + a2 * m2.y + a3 * m3.y);
    }
    __syncthreads();

    #pragma unroll
    for (int e = 0; e < 8; ++e) {
        const int idx4 = e * 256 + t;     // 2048 float4 groups (128 rows x 16)
        const int row  = idx4 >> 4;
        const int c4   = (idx4 & 15) * 4;
        const int off  = row * 64 + c4;
        const float a0 = sA0[row], li = sLi[row];
        float4 po = *(float4*)&Op[off];
        po.x *= a0; po.y *= a0; po.z *= a0; po.w *= a0;
        {
            const float a1 = sA1[row];
            const ushort4 u = *(const ushort4*)&p1[off];
            po.x += a1 * bf2f(u.x); po.y += a1 * bf2f(u.y);
            po.z += a1 * bf2f(u.z); po.w += a1 * bf2f(u.w);
        }
        if (n > 2) {
            const float a2 = sA2[row];
            const ushort4 u = *(const ushort4*)&p2[off];
            po.x += a2 * bf2f(u.x); po.y += a2 * bf2f(u.y);
            po.z += a2 * bf2f(u.z); po.w += a2 * bf2f(u.w);
        }
        if (n > 3) {
            const float a3 = sA3[row];
            const ushort4 u = *(const ushort4*)&p3[off];
            po.x += a3 * bf2f(u.x); po.y += a3 * bf2f(u.y);
            po.z += a3 * bf2f(u.z); po.w += a3 * bf2f(u.w);
        }
        po.x *= li; po.y *= li; po.z *= li; po.w *= li;
        *(float4*)&Op[off] = po;
    }
}

extern "C" void kernel_launch(void* const* d_in, const int* in_sizes, int n_in,
                              void* d_out, int out_size, void* d_ws, size_t ws_size,
                              hipStream_t stream) {
    const float* Q = (const float*)d_in[0];
    const float* K = (const float*)d_in[1];
    const float* V = (const float*)d_in[2];
    float* O = (float*)d_out;
    if (ws_size >= WS_NEED) {
        fattn_kernel<2><<<dim3(1280), dim3(256), 0, stream>>>(Q, K, V, O, (char*)d_ws);
        merge_kernel<<<dim3(512), dim3(256), 0, stream>>>(O, (const char*)d_ws);
    } else {                                     // ws too small: fallback schedule
        fattn_kernel<0><<<dim3(512), dim3(256), 0, stream>>>(Q, K, V, O, (char*)d_ws);
    }
}